// Round 8
// baseline (181.931 us; speedup 1.0000x reference)
//
#include <hip/hip_runtime.h>
#include <math.h>

// Problem dims
#define B_   512
#define F_   1024
#define H1_  512
#define H2_  256
#define OUT_ 128
#define KD_  5
#define NT_  640
#define ZK_  384   // H2_ + OUT_

typedef short bf16x8 __attribute__((ext_vector_type(8)));
typedef float f32x16 __attribute__((ext_vector_type(16)));

__device__ __forceinline__ float lrelu(float v) { return v >= 0.f ? v : 0.2f * v; }

// fp32 -> bf16 round-to-nearest-even
__device__ __forceinline__ unsigned f2bf(float f) {
    unsigned u = __float_as_uint(f);
    return (u + 0x7fffu + ((u >> 16) & 1u)) >> 16;
}
__device__ __forceinline__ unsigned pack2bf(float a, float b) {
    return f2bf(a) | (f2bf(b) << 16);
}

// ---------------------------------------------------------------------------
// MFMA fragment loaders (verified layouts — R0/R1 sessions, absmax 5.9e-3)
// ---------------------------------------------------------------------------
__device__ __forceinline__ bf16x8 frag_bf16row(const unsigned short* p, int idx, int ld, int k) {
    return *(const bf16x8*)(p + (size_t)idx * ld + k);
}
__device__ __forceinline__ bf16x8 frag_f32row(const float* p, int idx, int ld, int k) {
    const float4 a = *(const float4*)(p + (size_t)idx * ld + k);
    const float4 b = *(const float4*)(p + (size_t)idx * ld + k + 4);
    union { unsigned u[4]; bf16x8 v; } cv;
    cv.u[0] = pack2bf(a.x, a.y); cv.u[1] = pack2bf(a.z, a.w);
    cv.u[2] = pack2bf(b.x, b.y); cv.u[3] = pack2bf(b.z, b.w);
    return cv.v;
}
// column gather from fp32 [K][ld] matrix: element j = p[(k+j)*ld + idx]
__device__ __forceinline__ bf16x8 frag_f32col(const float* p, int idx, int ld, int k) {
    union { unsigned u[4]; bf16x8 v; } cv;
    #pragma unroll
    for (int jj = 0; jj < 4; ++jj)
        cv.u[jj] = pack2bf(p[(size_t)(k + 2 * jj) * ld + idx],
                           p[(size_t)(k + 2 * jj + 1) * ld + idx]);
    return cv.v;
}

#define M_BF16ROW 0
#define M_F32ROW  1
#define M_F32COL  2

// ---------------------------------------------------------------------------
// Grid barrier, load-polling version (non-cooperative; 256 blocks co-resident:
// 32KiB LDS / 32 VGPR / 8 waves per block — far under per-CU limits).
// Single root counter. Arrival = one relaxed agent-scope RMW per block;
// POLLS ARE RELAXED AGENT-SCOPE LOADS (concurrently serviced by the LLC —
// R6's 16us/barrier was RMW-poll serialization on the atomic pipe).
// Monotonic generations; zeroed by hipMemsetAsync per launch.
// Guard capped at 20k iters (~4ms): a barrier bug fails absmax quickly
// instead of timing out the container.
// ---------------------------------------------------------------------------
__device__ __forceinline__ void gbar(unsigned* bar, unsigned gen) {
    __syncthreads();
    if (threadIdx.x == 0) {
        __threadfence();                          // release this block's writes
        __hip_atomic_fetch_add(bar, 1u, __ATOMIC_RELAXED, __HIP_MEMORY_SCOPE_AGENT);
        const unsigned target = 256u * gen;
        int guard = 0;
        while (__hip_atomic_load(bar, __ATOMIC_RELAXED, __HIP_MEMORY_SCOPE_AGENT) < target
               && ++guard < 20000)
            __builtin_amdgcn_s_sleep(1);
        __threadfence();                          // acquire remote writes
    }
    __syncthreads();
}

// ---------------------------------------------------------------------------
// One 32x32 output tile, K split across 8 waves (barrier-free K-loop,
// single LDS reduction). Verbatim R1/R6 device code (verified).
// ---------------------------------------------------------------------------
template<int KSLICE, int AMODE, int BMODE, bool RELU, bool HAS_BIAS, bool BF16_OUT>
__device__ __forceinline__
void gemm_tile(float* Red,
               const void* __restrict__ Ap, const void* __restrict__ Bp,
               const float* __restrict__ bias, void* __restrict__ Cout,
               int N, int LDA, int LDB, int m0, int n0, int tid)
{
    const int wav  = tid >> 6;
    const int lane = tid & 63;
    const int half = lane >> 5;
    const int mn   = lane & 31;

    f32x16 acc;
    #pragma unroll
    for (int i = 0; i < 16; ++i) acc[i] = 0.f;

    #pragma unroll
    for (int s = 0; s < KSLICE / 16; ++s) {
        const int k = wav * KSLICE + 16 * s + 8 * half;
        bf16x8 af, bf;
        if (AMODE == M_BF16ROW)      af = frag_bf16row((const unsigned short*)Ap, m0 + mn, LDA, k);
        else if (AMODE == M_F32ROW)  af = frag_f32row((const float*)Ap, m0 + mn, LDA, k);
        else                         af = frag_f32col((const float*)Ap, m0 + mn, LDA, k);
        if (BMODE == M_BF16ROW)      bf = frag_bf16row((const unsigned short*)Bp, n0 + mn, LDB, k);
        else                         bf = frag_f32col((const float*)Bp, n0 + mn, LDB, k);
        acc = __builtin_amdgcn_mfma_f32_32x32x16_bf16(af, bf, acc, 0, 0, 0);
    }

    // C/D layout (verified): col = lane&31, row = (reg&3) + 8*(reg>>2) + 4*(lane>>5)
    #pragma unroll
    for (int r = 0; r < 16; ++r) {
        const int row = (r & 3) + 8 * (r >> 2) + 4 * half;
        Red[wav * 1024 + row * 32 + mn] = acc[r];
    }
    __syncthreads();

    if (tid < 256) {
        const int e0 = tid * 4, row = e0 >> 5, col = e0 & 31;
        float v[4];
        #pragma unroll
        for (int q = 0; q < 4; ++q) {
            float u = 0.f;
            #pragma unroll
            for (int w = 0; w < 8; ++w) u += Red[w * 1024 + e0 + q];
            if (HAS_BIAS) u += bias[n0 + col + q];
            if (RELU) u = lrelu(u);
            v[q] = u;
        }
        if (BF16_OUT) {
            uint2 o;
            o.x = pack2bf(v[0], v[1]); o.y = pack2bf(v[2], v[3]);
            *(uint2*)((unsigned short*)Cout + (size_t)(m0 + row) * N + n0 + col) = o;
        } else {
            *(float4*)((float*)Cout + (size_t)(m0 + row) * N + n0 + col) =
                make_float4(v[0], v[1], v[2], v[3]);
        }
    }
    __syncthreads();
}

// ---------------------------------------------------------------------------
// Minibatch discrimination phase (verbatim R1/R6, verified): block b ->
// (o=b>>1, jh=b&1); thread -> (t=tid&255 -> j=jh*256+t, ih=tid>>8).
// obF[o][j] full sum.
// ---------------------------------------------------------------------------
__device__ __forceinline__
void disc_phase(float* S, const float* __restrict__ Mt, float* __restrict__ obF,
                int b, int tid)
{
    float* L = S;          // [512][8] fp32 staging of Mt rows o*5..o*5+4
    float* P = S + 4096;   // [256] i-half partial
    const int o  = b >> 1;
    const int jh = b & 1;
    const int t  = tid & 255;
    const int ih = tid >> 8;
    const float* base = Mt + (size_t)o * (KD_ * 512);

    #pragma unroll
    for (int k = 0; k < KD_; ++k)
        L[tid * 8 + k] = base[k * 512 + tid];

    const int j = jh * 256 + t;
    const float mj0 = base[0 * 512 + j], mj1 = base[1 * 512 + j],
                mj2 = base[2 * 512 + j], mj3 = base[3 * 512 + j],
                mj4 = base[4 * 512 + j];
    __syncthreads();

    const int i0 = ih * 256;
    float acc0 = 0.f, acc1 = 0.f;
    #pragma unroll 4
    for (int i = 0; i < 256; i += 2) {
        {
            const float4 a = *(const float4*)&L[(i0 + i) * 8];
            const float n = fabsf(a.x - mj0) + fabsf(a.y - mj1) + fabsf(a.z - mj2)
                          + fabsf(a.w - mj3) + fabsf(L[(i0 + i) * 8 + 4] - mj4);
            acc0 += __expf(-n);
        }
        {
            const float4 a = *(const float4*)&L[(i0 + i + 1) * 8];
            const float n = fabsf(a.x - mj0) + fabsf(a.y - mj1) + fabsf(a.z - mj2)
                          + fabsf(a.w - mj3) + fabsf(L[(i0 + i + 1) * 8 + 4] - mj4);
            acc1 += __expf(-n);
        }
    }
    if (ih == 0) P[t] = acc0 + acc1;
    __syncthreads();
    if (ih == 1) obF[(size_t)o * B_ + j] = P[t] + acc0 + acc1 - 1.0f;  // -1: self term
    __syncthreads();
}

// ---------------------------------------------------------------------------
// Final GEMM3 + dot phase (verbatim R1/R6, verified): wave w -> col-tile
// n0=(w&3)*32, K-half kh=w>>2; partials summed in LDS, bias+lrelu in dot.
// ---------------------------------------------------------------------------
__device__ __forceinline__
void final_phase(float* Red, const unsigned short* __restrict__ h2b,
                 const float* __restrict__ obF,
                 const float* __restrict__ W3, const float* __restrict__ b3,
                 const float* __restrict__ W4, const float* __restrict__ b4,
                 float* __restrict__ out, int m0, int tid)
{
    const int w    = tid >> 6;
    const int lane = tid & 63;
    const int half = lane >> 5;
    const int mn   = lane & 31;
    const int n0   = (w & 3) * 32;
    const int kh   = w >> 2;

    f32x16 acc;
    #pragma unroll
    for (int i = 0; i < 16; ++i) acc[i] = 0.f;

    #pragma unroll
    for (int s = 0; s < 12; ++s) {
        const int k = kh * 192 + 16 * s + 8 * half;
        const int idx = m0 + mn;
        bf16x8 af;
        if (k < H2_) af = frag_bf16row(h2b, idx, H2_, k);
        else         af = frag_f32col(obF, idx, B_, k - H2_);
        const bf16x8 bf = frag_f32col(W3, n0 + mn, OUT_, k);
        acc = __builtin_amdgcn_mfma_f32_32x32x16_bf16(af, bf, acc, 0, 0, 0);
    }

    #pragma unroll
    for (int r = 0; r < 16; ++r) {
        const int row = (r & 3) + 8 * (r >> 2) + 4 * half;
        Red[kh * 4096 + row * 128 + n0 + mn] = acc[r];
    }
    __syncthreads();

    if (tid < 128) {
        const int row = tid >> 2, q = tid & 3;
        float a = 0.f;
        #pragma unroll
        for (int cc0 = 0; cc0 < 32; ++cc0) {
            const int cc = (cc0 + tid) & 31;       // rotation: 2-way LDS aliasing (free)
            const int c = q * 32 + cc;
            const float u = lrelu(Red[row * 128 + c] + Red[4096 + row * 128 + c] + b3[c]);
            a += u * W4[c];
        }
        a += __shfl_down(a, 2, 4);
        a += __shfl_down(a, 1, 4);
        if (q == 0) out[m0 + row] = a + b4[0];
    }
}

// ---------------------------------------------------------------------------
// Mega-kernel: 256 blocks x 512 threads, REGULAR launch (graph-capturable),
// 4 load-polling barriers replace 4 kernel boundaries. Phases verbatim R1/R6.
// ---------------------------------------------------------------------------
__global__ __launch_bounds__(512)
void mega4(const float* __restrict__ x,  const float* __restrict__ W1, const float* __restrict__ b1,
           const float* __restrict__ W2, const float* __restrict__ b2,
           const float* __restrict__ T,
           const float* __restrict__ W3, const float* __restrict__ b3,
           const float* __restrict__ W4, const float* __restrict__ b4,
           float* __restrict__ Mt, float* __restrict__ obF,
           unsigned short* __restrict__ h1b, unsigned short* __restrict__ h2b,
           unsigned* __restrict__ bar, float* __restrict__ out)
{
    __shared__ float S[8192];   // 32 KiB, reused by every phase
    const int b   = blockIdx.x;
    const int tid = threadIdx.x;

    // Ph1: h1 = lrelu(x @ W1 + b1) -> bf16 [512][512]; 256 tiles (16x16)
    gemm_tile<128, M_F32ROW, M_F32COL, true, true, true>(
        S, x, W1, b1, h1b, H1_, F_, H1_, (b >> 4) * 32, (b & 15) * 32, tid);
    gbar(bar, 1);

    // Ph2: h2 = lrelu(h1 @ W2 + b2) -> bf16 [512][256]; 128 tiles
    if (b < 128)
        gemm_tile<64, M_BF16ROW, M_F32COL, true, true, true>(
            S, h1b, W2, b2, h2b, H2_, H1_, H2_, (b >> 3) * 32, (b & 7) * 32, tid);
    gbar(bar, 2);

    // Ph3: Mt = (h2 @ T)^T -> fp32 [640][512]; 320 tiles grid-strided
    for (int t = b; t < 320; t += 256)
        gemm_tile<32, M_F32COL, M_BF16ROW, false, false, false>(
            S, T, h2b, nullptr, Mt, B_, NT_, H2_, (t / 16) * 32, (t % 16) * 32, tid);
    gbar(bar, 3);

    // Ph4: minibatch discrimination -> obF fp32 [128][512] (full sum)
    disc_phase(S, Mt, obF, b, tid);
    gbar(bar, 4);

    // Ph5: out = lrelu(concat([h2, ob]) @ W3 + b3) @ W4 + b4; 16 row strips
    if (b < 16)
        final_phase(S, h2b, obF, W3, b3, W4, b4, out, b * 32, tid);
}

extern "C" void kernel_launch(void* const* d_in, const int* in_sizes, int n_in,
                              void* d_out, int out_size, void* d_ws, size_t ws_size,
                              hipStream_t stream) {
    const float* x  = (const float*)d_in[0];   // (512, 1024)
    const float* W1 = (const float*)d_in[1];   // (1024, 512)
    const float* b1 = (const float*)d_in[2];   // (512,)
    const float* W2 = (const float*)d_in[3];   // (512, 256)
    const float* b2 = (const float*)d_in[4];   // (256,)
    const float* T  = (const float*)d_in[5];   // (256, 640) flat
    const float* W3 = (const float*)d_in[6];   // (384, 128)
    const float* b3 = (const float*)d_in[7];   // (128,)
    const float* W4 = (const float*)d_in[8];   // (128, 1)
    const float* b4 = (const float*)d_in[9];   // (1,)
    float* out = (float*)d_out;                // (512,)

    char* ws = (char*)d_ws;
    float*          Mt  = (float*)(ws + 0);                  // 640*512*4   = 1310720
    float*          obF = (float*)(ws + 1310720);            // 128*512*4   =  262144
    unsigned short* h1b = (unsigned short*)(ws + 1572864);   // 512*512*2   =  524288
    unsigned short* h2b = (unsigned short*)(ws + 2097152);   // 512*256*2   =  262144
    unsigned*       bar = (unsigned*)(ws + 2359296);         // root counter line
    // total 2,359,424 bytes

    hipMemsetAsync(bar, 0, 128, stream);   // zero barrier state (graph-capturable)

    mega4<<<256, 512, 0, stream>>>(x, W1, b1, W2, b2, T, W3, b3, W4, b4,
                                   Mt, obF, h1b, h2b, bar, out);
}

// Round 9
// 109.111 us; speedup vs baseline: 1.6674x; 1.6674x over previous
//
#include <hip/hip_runtime.h>
#include <math.h>

// Problem dims
#define B_   512
#define F_   1024
#define H1_  512
#define H2_  256
#define OUT_ 128
#define KD_  5
#define NT_  640
#define ZK_  384   // H2_ + OUT_

typedef short bf16x8 __attribute__((ext_vector_type(8)));
typedef float f32x16 __attribute__((ext_vector_type(16)));

__device__ __forceinline__ float lrelu(float v) { return v >= 0.f ? v : 0.2f * v; }

// fp32 -> bf16 round-to-nearest-even
__device__ __forceinline__ unsigned f2bf(float f) {
    unsigned u = __float_as_uint(f);
    return (u + 0x7fffu + ((u >> 16) & 1u)) >> 16;
}
__device__ __forceinline__ unsigned pack2bf(float a, float b) {
    return f2bf(a) | (f2bf(b) << 16);
}

// ---------------------------------------------------------------------------
// MFMA fragment loaders (A/B lane layout: idx = lane&31, k = (lane>>5)*8 + j,
// j = 0..7 contiguous). All verified (absmax 5.9e-3).
// ---------------------------------------------------------------------------
__device__ __forceinline__ bf16x8 frag_bf16row(const unsigned short* p, int idx, int ld, int k) {
    return *(const bf16x8*)(p + (size_t)idx * ld + k);
}
__device__ __forceinline__ bf16x8 frag_f32row(const float* p, int idx, int ld, int k) {
    const float4 a = *(const float4*)(p + (size_t)idx * ld + k);
    const float4 b = *(const float4*)(p + (size_t)idx * ld + k + 4);
    union { unsigned u[4]; bf16x8 v; } cv;
    cv.u[0] = pack2bf(a.x, a.y); cv.u[1] = pack2bf(a.z, a.w);
    cv.u[2] = pack2bf(b.x, b.y); cv.u[3] = pack2bf(b.z, b.w);
    return cv.v;
}
// column gather from fp32 [K][ld] matrix: element j = p[(k+j)*ld + idx]
__device__ __forceinline__ bf16x8 frag_f32col(const float* p, int idx, int ld, int k) {
    union { unsigned u[4]; bf16x8 v; } cv;
    #pragma unroll
    for (int jj = 0; jj < 4; ++jj)
        cv.u[jj] = pack2bf(p[(size_t)(k + 2 * jj) * ld + idx],
                           p[(size_t)(k + 2 * jj + 1) * ld + idx]);
    return cv.v;
}
// concat([h2b bf16 (ld 256), obA+obB fp32 (ld 128)]) row, K=384
__device__ __forceinline__ bf16x8 frag_concat(const unsigned short* h2b,
                                              const float* obA, const float* obB,
                                              int idx, int k) {
    if (k < H2_) return frag_bf16row(h2b, idx, H2_, k);
    const float* pa = obA + (size_t)idx * OUT_ + (k - H2_);
    const float* pb = obB + (size_t)idx * OUT_ + (k - H2_);
    union { unsigned u[4]; bf16x8 v; } cv;
    #pragma unroll
    for (int jj = 0; jj < 4; ++jj)
        cv.u[jj] = pack2bf(pa[2 * jj] + pb[2 * jj], pa[2 * jj + 1] + pb[2 * jj + 1]);
    return cv.v;
}

// operand modes
#define M_BF16ROW 0
#define M_F32ROW  1
#define M_F32COL  2

// ---------------------------------------------------------------------------
// Barrier-free MFMA GEMM, one 32x32 tile per block, K split across WAVES
// waves (no barriers/LDS in the K-loop; single LDS reduction + epilogue).
// ---------------------------------------------------------------------------
template<int WAVES, int KSLICE, int AMODE, int BMODE,
         bool RELU, bool HAS_BIAS, bool BF16_OUT>
__global__ __launch_bounds__(WAVES * 64)
void gemm_k(const void* __restrict__ Ap, const void* __restrict__ Bp,
            const float* __restrict__ bias, void* __restrict__ Cout,
            int M, int N, int LDA, int LDB)
{
    __shared__ float Red[WAVES * 1024];
    const int tid  = threadIdx.x;
    const int wav  = tid >> 6;
    const int lane = tid & 63;
    const int half = lane >> 5;
    const int mn   = lane & 31;
    const int m0   = blockIdx.y * 32;
    const int n0   = blockIdx.x * 32;

    f32x16 acc;
    #pragma unroll
    for (int i = 0; i < 16; ++i) acc[i] = 0.f;

    #pragma unroll
    for (int s = 0; s < KSLICE / 16; ++s) {
        const int k = wav * KSLICE + 16 * s + 8 * half;
        bf16x8 af, bf;
        if (AMODE == M_BF16ROW)      af = frag_bf16row((const unsigned short*)Ap, m0 + mn, LDA, k);
        else if (AMODE == M_F32ROW)  af = frag_f32row((const float*)Ap, m0 + mn, LDA, k);
        else                         af = frag_f32col((const float*)Ap, m0 + mn, LDA, k);
        if (BMODE == M_BF16ROW)      bf = frag_bf16row((const unsigned short*)Bp, n0 + mn, LDB, k);
        else                         bf = frag_f32col((const float*)Bp, n0 + mn, LDB, k);
        acc = __builtin_amdgcn_mfma_f32_32x32x16_bf16(af, bf, acc, 0, 0, 0);
    }

    // C/D layout (verified): col = lane&31, row = (reg&3) + 8*(reg>>2) + 4*(lane>>5)
    #pragma unroll
    for (int r = 0; r < 16; ++r) {
        const int row = (r & 3) + 8 * (r >> 2) + 4 * half;
        Red[wav * 1024 + row * 32 + mn] = acc[r];
    }
    __syncthreads();

    if (tid < 256) {
        const int e0 = tid * 4, row = e0 >> 5, col = e0 & 31;
        float v[4];
        #pragma unroll
        for (int q = 0; q < 4; ++q) {
            float u = 0.f;
            #pragma unroll
            for (int w = 0; w < WAVES; ++w) u += Red[w * 1024 + e0 + q];
            if (HAS_BIAS) u += bias[n0 + col + q];
            if (RELU) u = lrelu(u);
            v[q] = u;
        }
        if (BF16_OUT) {
            uint2 o;
            o.x = pack2bf(v[0], v[1]); o.y = pack2bf(v[2], v[3]);
            *(uint2*)((unsigned short*)Cout + (size_t)(m0 + row) * N + n0 + col) = o;
        } else {
            *(float4*)((float*)Cout + (size_t)(m0 + row) * N + n0 + col) =
                make_float4(v[0], v[1], v[2], v[3]);
        }
    }
}

// ---------------------------------------------------------------------------
// Minibatch discrimination (verified): Mt fp32 [640][512],
// block = (o, j-quarter, i-half): 1024 blocks x 128 threads.
// obH[ih][j][o] = sum_{i in half} exp(-L1) - (self ? 1 : 0)
// ---------------------------------------------------------------------------
__global__ __launch_bounds__(128)
void disc_kernel(const float* __restrict__ Mt, float* __restrict__ obH)
{
    const int o  = blockIdx.x >> 3;
    const int jq = (blockIdx.x >> 1) & 3;
    const int ih = blockIdx.x & 1;
    const int t  = threadIdx.x;
    const int j  = jq * 128 + t;
    const int i0 = ih * 256;
    __shared__ float L[256 * 8];
    const float* base = Mt + (size_t)o * 5 * 512;
    #pragma unroll
    for (int k = 0; k < KD_; ++k) {
        L[t * 8 + k]         = base[k * 512 + i0 + t];
        L[(t + 128) * 8 + k] = base[k * 512 + i0 + t + 128];
    }
    const float mj0 = base[0 * 512 + j], mj1 = base[1 * 512 + j],
                mj2 = base[2 * 512 + j], mj3 = base[3 * 512 + j],
                mj4 = base[4 * 512 + j];
    __syncthreads();

    float acc0 = 0.f, acc1 = 0.f;
    #pragma unroll 4
    for (int i = 0; i < 256; i += 2) {
        {
            const float4 a = *(const float4*)&L[i * 8];
            const float n = fabsf(a.x - mj0) + fabsf(a.y - mj1) + fabsf(a.z - mj2)
                          + fabsf(a.w - mj3) + fabsf(L[i * 8 + 4] - mj4);
            acc0 += __expf(-n);
        }
        {
            const float4 a = *(const float4*)&L[(i + 1) * 8];
            const float n = fabsf(a.x - mj0) + fabsf(a.y - mj1) + fabsf(a.z - mj2)
                          + fabsf(a.w - mj3) + fabsf(L[(i + 1) * 8 + 4] - mj4);
            acc1 += __expf(-n);
        }
    }
    const float self = ((j >> 8) == ih) ? 1.f : 0.f;
    obH[(size_t)ih * B_ * OUT_ + (size_t)j * OUT_ + o] = acc0 + acc1 - self;
}

// ---------------------------------------------------------------------------
// Fused GEMM3 + final dot: 16 blocks x 256 threads. Block = 32-row strip.
// Wave w computes col-tile n0 = w*32 over full K=384 (concat A, W3 col
// gather B). Epilogue: bias+lrelu into Red[32][128], then rotated LDS dot
// with W4 -> out.
// ---------------------------------------------------------------------------
__global__ __launch_bounds__(256)
void gemm3_dot(const unsigned short* __restrict__ h2b,
               const float* __restrict__ obA, const float* __restrict__ obB,
               const float* __restrict__ W3, const float* __restrict__ b3,
               const float* __restrict__ W4, const float* __restrict__ b4,
               float* __restrict__ out)
{
    __shared__ float Red[32 * 128];
    const int tid  = threadIdx.x;
    const int w    = tid >> 6;
    const int lane = tid & 63;
    const int half = lane >> 5;
    const int mn   = lane & 31;
    const int m0   = blockIdx.x * 32;
    const int n0   = w * 32;

    f32x16 acc;
    #pragma unroll
    for (int i = 0; i < 16; ++i) acc[i] = 0.f;

    #pragma unroll
    for (int s = 0; s < ZK_ / 16; ++s) {
        const int k = 16 * s + 8 * half;
        const bf16x8 af = frag_concat(h2b, obA, obB, m0 + mn, k);
        const bf16x8 bf = frag_f32col(W3, n0 + mn, OUT_, k);
        acc = __builtin_amdgcn_mfma_f32_32x32x16_bf16(af, bf, acc, 0, 0, 0);
    }

    #pragma unroll
    for (int r = 0; r < 16; ++r) {
        const int row = (r & 3) + 8 * (r >> 2) + 4 * half;
        const int col = n0 + mn;
        Red[row * 128 + col] = lrelu(acc[r] + b3[col]);
    }
    __syncthreads();

    if (tid < 128) {
        const int row = tid >> 2, q = tid & 3;
        float a = 0.f;
        #pragma unroll
        for (int cc0 = 0; cc0 < 32; ++cc0) {
            const int cc = (cc0 + tid) & 31;       // rotation: 2-way LDS aliasing (free)
            a += Red[row * 128 + q * 32 + cc] * W4[q * 32 + cc];
        }
        a += __shfl_down(a, 2, 4);
        a += __shfl_down(a, 1, 4);
        if (q == 0) out[m0 + row] = a + b4[0];
    }
}

extern "C" void kernel_launch(void* const* d_in, const int* in_sizes, int n_in,
                              void* d_out, int out_size, void* d_ws, size_t ws_size,
                              hipStream_t stream) {
    const float* x  = (const float*)d_in[0];   // (512, 1024)
    const float* W1 = (const float*)d_in[1];   // (1024, 512)
    const float* b1 = (const float*)d_in[2];   // (512,)
    const float* W2 = (const float*)d_in[3];   // (512, 256)
    const float* b2 = (const float*)d_in[4];   // (256,)
    const float* T  = (const float*)d_in[5];   // (256, 640) flat
    const float* W3 = (const float*)d_in[6];   // (384, 128)
    const float* b3 = (const float*)d_in[7];   // (128,)
    const float* W4 = (const float*)d_in[8];   // (128, 1)
    const float* b4 = (const float*)d_in[9];   // (1,)
    float* out = (float*)d_out;                // (512,)

    char* ws = (char*)d_ws;
    float*          Mt  = (float*)(ws + 0);                  // 640*512*4   = 1310720
    float*          obH = (float*)(ws + 1310720);            // 2*512*128*4 =  524288
    unsigned short* h1b = (unsigned short*)(ws + 1835008);   // 512*512*2   =  524288
    unsigned short* h2b = (unsigned short*)(ws + 2359296);   // 512*256*2   =  262144
    // total 2,621,440 bytes

    // 1) h1 = lrelu(x @ W1 + b1)  (512x512, K=1024) -> bf16
    //    A: fp32 rows of x ; B: fp32 column gather of W1
    gemm_k<8, 128, M_F32ROW, M_F32COL, true, true, true>
        <<<dim3(H1_ / 32, B_ / 32), 512, 0, stream>>>(
        x, W1, b1, h1b, B_, H1_, F_, H1_);

    // 2) h2 = lrelu(h1 @ W2 + b2) (512x256, K=512) -> bf16
    gemm_k<8, 64, M_BF16ROW, M_F32COL, true, true, true>
        <<<dim3(H2_ / 32, B_ / 32), 512, 0, stream>>>(
        h1b, W2, b2, h2b, B_, H2_, H1_, H2_);

    // 3) Mt = (h2 @ T)^T directly: A = T columns (fp32 gather, ld 640),
    //    B = h2b rows (bf16) -> Mt fp32 [640][512]
    gemm_k<4, 64, M_F32COL, M_BF16ROW, false, false, false>
        <<<dim3(B_ / 32, NT_ / 32), 256, 0, stream>>>(
        T, h2b, nullptr, Mt, NT_, B_, NT_, H2_);

    // 4) minibatch discrimination -> obH (two i-half partials)
    disc_kernel<<<1024, 128, 0, stream>>>(Mt, obH);

    // 5) out = (lrelu(concat([h2, ob]) @ W3 + b3)) @ W4 + b4
    gemm3_dot<<<B_ / 32, 256, 0, stream>>>(
        h2b, obH, obH + B_ * OUT_, W3, b3, W4, b4, out);
}